// Round 4
// baseline (6415.133 us; speedup 1.0000x reference)
//
#include <hip/hip_runtime.h>
#include <stdint.h>

#define NN 8192
#define D 256
#define DA 64
#define CAND 2048
#define BMX 128
#define BKX 64

typedef unsigned short ushort_t;

// ---- f32 block reductions (256-thread blocks, 4 waves) ----
__device__ float blockSumF(float v, float* scr) {
  __syncthreads();
#pragma unroll
  for (int o = 32; o > 0; o >>= 1) v += __shfl_down(v, o, 64);
  if ((threadIdx.x & 63) == 0) scr[threadIdx.x >> 6] = v;
  __syncthreads();
  return ((scr[0] + scr[1]) + (scr[2] + scr[3]));
}
__device__ float blockMaxF(float v, float* scr) {
  __syncthreads();
#pragma unroll
  for (int o = 32; o > 0; o >>= 1) v = fmaxf(v, __shfl_down(v, o, 64));
  if ((threadIdx.x & 63) == 0) scr[threadIdx.x >> 6] = v;
  __syncthreads();
  return fmaxf(fmaxf(scr[0], scr[1]), fmaxf(scr[2], scr[3]));
}
// ---- inclusive prefix scan across 256 threads (4 waves) ----
__device__ float blockScanIncl(float v, float* wscr) {
#pragma unroll
  for (int off = 1; off < 64; off <<= 1) {
    float u = __shfl_up(v, off, 64);
    if ((threadIdx.x & 63) >= off) v += u;
  }
  __syncthreads();                    // protect wscr reuse
  if ((threadIdx.x & 63) == 63) wscr[threadIdx.x >> 6] = v;
  __syncthreads();
  float add = 0.0f;
  int wid = threadIdx.x >> 6;
  for (int w = 0; w < wid; w++) add += wscr[w];
  return v + add;
}

// ---- zero a float buffer ----
__global__ void zero_kernel(float* __restrict__ p, size_t n) {
  for (size_t i = (size_t)blockIdx.x * blockDim.x + threadIdx.x; i < n;
       i += (size_t)gridDim.x * blockDim.x)
    p[i] = 0.0f;
}

// ---- den[i] = 1 + sum_j S[i][j] ----
__global__ __launch_bounds__(256) void rowsum_kernel(const float* __restrict__ S, float* __restrict__ den) {
  __shared__ float scr[4];
  int row = blockIdx.x, tid = threadIdx.x;
  const float* sr = S + (size_t)row * NN;
  float s = 0;
  for (int c = tid * 4; c < NN; c += 1024) {
    float4 u = *(const float4*)(sr + c);
    s += (u.x + u.y) + (u.z + u.w);
  }
  float tot = blockSumF(s, scr);
  if (tid == 0) den[row] = tot + 1.0f;
}

// ---- Xf_next = (S@Xf + Xf)/den : 128x64 tile, 8x4/thread, swizzled A ----
// A stored transposed+XOR-swizzled: element (row r, k) at Ast[k][r ^ ((k>>2)<<3)].
// Reads: float4 at Ast[k][(ty*8)^sw] (+4) -> broadcast within wave, 0-conflict.
// Writes: 4-way conflict (was 8-way at stride 68). Global loads for tile kt+1
// issued before compute on kt (reg double-buffer). Per-output summation order
// identical to previous version (k ascending, one fmaf per k).
__global__ __launch_bounds__(256) void xf_gemm(const float* __restrict__ S,
                                               const float* __restrict__ XfC,
                                               const float* __restrict__ den,
                                               float* __restrict__ XfN) {
  __shared__ float Ast[BKX][BMX];   // 32 KB
  __shared__ float Bs[BKX][68];     // 17.4 KB
  int tid = threadIdx.x;
  int tx = tid & 15, ty = tid >> 4;
  int rb = blockIdx.x * BMX;
  int cb = blockIdx.y * 64;
  float acc[8][4] = {};
  float4 aR[8], bR[4];
  int c4 = tid & 15;

#define STAGE_ISSUE(kt)                                                        \
  {                                                                            \
    _Pragma("unroll")                                                          \
    for (int t = 0; t < 8; t++) {                                              \
      int i4 = tid + 256 * t; int r = i4 >> 4;                                 \
      aR[t] = *(const float4*)(S + (size_t)(rb + r) * NN + (kt) + c4 * 4);     \
    }                                                                          \
    _Pragma("unroll")                                                          \
    for (int t = 0; t < 4; t++) {                                              \
      int i4 = tid + 256 * t; int r = i4 >> 4;                                 \
      bR[t] = *(const float4*)(XfC + (size_t)((kt) + r) * D + cb + c4 * 4);    \
    }                                                                          \
  }
#define STAGE_WRITE()                                                          \
  {                                                                            \
    int sw = c4 << 3;                                                          \
    _Pragma("unroll")                                                          \
    for (int t = 0; t < 8; t++) {                                              \
      int i4 = tid + 256 * t; int rp = (i4 >> 4) ^ sw;                         \
      Ast[4 * c4 + 0][rp] = aR[t].x;                                           \
      Ast[4 * c4 + 1][rp] = aR[t].y;                                           \
      Ast[4 * c4 + 2][rp] = aR[t].z;                                           \
      Ast[4 * c4 + 3][rp] = aR[t].w;                                           \
    }                                                                          \
    _Pragma("unroll")                                                          \
    for (int t = 0; t < 4; t++) {                                              \
      int i4 = tid + 256 * t; int r = i4 >> 4;                                 \
      *(float4*)(&Bs[r][c4 * 4]) = bR[t];                                      \
    }                                                                          \
  }

  STAGE_ISSUE(0);
  STAGE_WRITE();
  __syncthreads();
  for (int kt = 0; kt < NN; kt += BKX) {
    if (kt + BKX < NN) STAGE_ISSUE(kt + BKX);
#pragma unroll 8
    for (int k = 0; k < BKX; k++) {
      int sw = ((k >> 2) & 15) << 3;
      int ra = (ty * 8) ^ sw;
      float4 a0 = *(const float4*)&Ast[k][ra];
      float4 a1 = *(const float4*)&Ast[k][ra + 4];
      float4 bv = *(const float4*)&Bs[k][tx * 4];
      acc[0][0] = fmaf(a0.x, bv.x, acc[0][0]); acc[0][1] = fmaf(a0.x, bv.y, acc[0][1]);
      acc[0][2] = fmaf(a0.x, bv.z, acc[0][2]); acc[0][3] = fmaf(a0.x, bv.w, acc[0][3]);
      acc[1][0] = fmaf(a0.y, bv.x, acc[1][0]); acc[1][1] = fmaf(a0.y, bv.y, acc[1][1]);
      acc[1][2] = fmaf(a0.y, bv.z, acc[1][2]); acc[1][3] = fmaf(a0.y, bv.w, acc[1][3]);
      acc[2][0] = fmaf(a0.z, bv.x, acc[2][0]); acc[2][1] = fmaf(a0.z, bv.y, acc[2][1]);
      acc[2][2] = fmaf(a0.z, bv.z, acc[2][2]); acc[2][3] = fmaf(a0.z, bv.w, acc[2][3]);
      acc[3][0] = fmaf(a0.w, bv.x, acc[3][0]); acc[3][1] = fmaf(a0.w, bv.y, acc[3][1]);
      acc[3][2] = fmaf(a0.w, bv.z, acc[3][2]); acc[3][3] = fmaf(a0.w, bv.w, acc[3][3]);
      acc[4][0] = fmaf(a1.x, bv.x, acc[4][0]); acc[4][1] = fmaf(a1.x, bv.y, acc[4][1]);
      acc[4][2] = fmaf(a1.x, bv.z, acc[4][2]); acc[4][3] = fmaf(a1.x, bv.w, acc[4][3]);
      acc[5][0] = fmaf(a1.y, bv.x, acc[5][0]); acc[5][1] = fmaf(a1.y, bv.y, acc[5][1]);
      acc[5][2] = fmaf(a1.y, bv.z, acc[5][2]); acc[5][3] = fmaf(a1.y, bv.w, acc[5][3]);
      acc[6][0] = fmaf(a1.z, bv.x, acc[6][0]); acc[6][1] = fmaf(a1.z, bv.y, acc[6][1]);
      acc[6][2] = fmaf(a1.z, bv.z, acc[6][2]); acc[6][3] = fmaf(a1.z, bv.w, acc[6][3]);
      acc[7][0] = fmaf(a1.w, bv.x, acc[7][0]); acc[7][1] = fmaf(a1.w, bv.y, acc[7][1]);
      acc[7][2] = fmaf(a1.w, bv.z, acc[7][2]); acc[7][3] = fmaf(a1.w, bv.w, acc[7][3]);
    }
    __syncthreads();
    if (kt + BKX < NN) {
      STAGE_WRITE();
    }
    __syncthreads();
  }
#pragma unroll
  for (int i = 0; i < 8; i++) {
    int r = rb + ty * 8 + i;
    float dinv = 1.0f / den[r];
#pragma unroll
    for (int j = 0; j < 4; j++) {
      int c = cb + tx * 4 + j;
      XfN[(size_t)r * D + c] = (acc[i][j] + XfC[(size_t)r * D + c]) * dinv;
    }
  }
#undef STAGE_ISSUE
#undef STAGE_WRITE
}

// ---- q,k f32: T1 = Xa@W1^T (materialized), q = T1@W2^T, k = Xa@W3^T ----
__global__ __launch_bounds__(64) void qk32_kernel(const float* __restrict__ Xa,
    const float* __restrict__ W1, const float* __restrict__ W2, const float* __restrict__ W3,
    float* __restrict__ qf, float* __restrict__ kf) {
  __shared__ float x[D];
  __shared__ float ts[DA];
  int row = blockIdx.x, tid = threadIdx.x;
  for (int i = tid; i < D; i += 64) x[i] = Xa[(size_t)row * D + i];
  __syncthreads();
  const float* w1r = W1 + (size_t)tid * D;
  const float* w3r = W3 + (size_t)tid * D;
  float t = 0.0f, kv = 0.0f;
  for (int d = 0; d < D; d++) {
    float xv = x[d];
    t  = fmaf(xv, w1r[d], t);
    kv = fmaf(xv, w3r[d], kv);
  }
  kf[(size_t)row * DA + tid] = kv;
  ts[tid] = t;
  __syncthreads();
  const float* w2r = W2 + (size_t)tid * DA;
  float qv = 0.0f;
  for (int a = 0; a < DA; a++) qv = fmaf(ts[a], w2r[a], qv);
  qf[(size_t)row * DA + tid] = qv;
}

// ---- L[chunk] = q @ k^T  f32 ----
__global__ __launch_bounds__(256) void logits32(const float* __restrict__ qf,
    const float* __restrict__ kf, float* __restrict__ L, int rowBase) {
  __shared__ float qs[64][65];
  __shared__ float ks[64][65];
  int tid = threadIdx.x;
  int tx = tid & 15, ty = tid >> 4;
  int colTile = blockIdx.x * 64;
  int rowTile = blockIdx.y * 64;
  for (int i = tid; i < 4096; i += 256) {
    int r = i >> 6, c = i & 63;
    qs[c][r] = qf[(size_t)(rowBase + rowTile + r) * DA + c];
    ks[c][r] = kf[(size_t)(colTile + r) * DA + c];
  }
  __syncthreads();
  float acc[4][4] = {};
  for (int c = 0; c < 64; c++) {
    float a0 = qs[c][ty * 4], a1 = qs[c][ty * 4 + 1];
    float a2 = qs[c][ty * 4 + 2], a3 = qs[c][ty * 4 + 3];
    float b0 = ks[c][tx * 4], b1 = ks[c][tx * 4 + 1];
    float b2 = ks[c][tx * 4 + 2], b3 = ks[c][tx * 4 + 3];
    acc[0][0] = fmaf(a0, b0, acc[0][0]); acc[0][1] = fmaf(a0, b1, acc[0][1]);
    acc[0][2] = fmaf(a0, b2, acc[0][2]); acc[0][3] = fmaf(a0, b3, acc[0][3]);
    acc[1][0] = fmaf(a1, b0, acc[1][0]); acc[1][1] = fmaf(a1, b1, acc[1][1]);
    acc[1][2] = fmaf(a1, b2, acc[1][2]); acc[1][3] = fmaf(a1, b3, acc[1][3]);
    acc[2][0] = fmaf(a2, b0, acc[2][0]); acc[2][1] = fmaf(a2, b1, acc[2][1]);
    acc[2][2] = fmaf(a2, b2, acc[2][2]); acc[2][3] = fmaf(a2, b3, acc[2][3]);
    acc[3][0] = fmaf(a3, b0, acc[3][0]); acc[3][1] = fmaf(a3, b1, acc[3][1]);
    acc[3][2] = fmaf(a3, b2, acc[3][2]); acc[3][3] = fmaf(a3, b3, acc[3][3]);
  }
#pragma unroll
  for (int i = 0; i < 4; i++)
#pragma unroll
    for (int j = 0; j < 4; j++)
      L[(size_t)(rowTile + ty * 4 + i) * NN + colTile + tx * 4 + j] = acc[i][j];
}

// ---- FULL-ROW top-p via histogram refinement in e-space. ----
// Identity: kept-weights = e_j / sum_kept(e); the softmax division by Z cancels.
// Z (= sum of e) is needed only as the cutoff scale: keep while cumsum(e) < 0.9*Z.
// One exp pass computes e, Z-partials, and the histogram together.
// 4-level refinement (8/8/8/4 bits) -> exact stop value + idx tie-break.
__global__ __launch_bounds__(256) void topp_histsel(const float* __restrict__ L,
    const float* __restrict__ XaOld, float* __restrict__ XaNew, int rowBase) {
  __shared__ float ps[NN];          // 32 KB: logits, then e-values (in place)
  __shared__ float hsum[256];       // per-bucket e-mass
  __shared__ float hcntf[256];      // per-bucket count
  __shared__ float cv[CAND];
  __shared__ ushort_t ci[CAND];
  __shared__ float wsum[4][256];
  __shared__ float wscr[4];
  __shared__ float scr[4];
  __shared__ unsigned sh_lo, sh_hi, sh_tie;
  __shared__ float sh_M, sh_asum, sh_hs;
  __shared__ int sh_C, sh_cross, sh_hc, sh_icut, sh_nkt, sh_ntot, sh_cnt;

  int tid = threadIdx.x;
  const float* Lr = L + (size_t)blockIdx.x * NN;
  // 1. load logits, row max
  float lm = -INFINITY;
  for (int c = tid * 4; c < NN; c += 1024) {
    float4 u = *(const float4*)(Lr + c);
    *(float4*)(ps + c) = u;
    lm = fmaxf(fmaxf(lm, fmaxf(u.x, u.y)), fmaxf(u.z, u.w));
  }
  float m = blockMaxF(lm, scr);   // entry barrier publishes ps
  hsum[tid] = 0.0f; hcntf[tid] = 0.0f;
  if (tid == 0) { sh_M = 0.0f; sh_C = 0; sh_cross = 256; }
  __syncthreads();
  // 2. single pass: e = exp(l-m) in (0,1], stored in place; Z partial; histogram.
  // Bucket = (bits>>20)-768 (exp + 3 mantissa bits, monotone). b<0 => e < 2^-31:
  // skipped; tail mass < 8192*2^-31 vs Z >= 1 => relative loss < 4e-6.
  float zp = 0.0f;
  for (int c = tid * 4; c < NN; c += 1024) {
    float4 u = *(const float4*)(ps + c);
    float4 ev;
    ev.x = expf(u.x - m); ev.y = expf(u.y - m);
    ev.z = expf(u.z - m); ev.w = expf(u.w - m);
    *(float4*)(ps + c) = ev;
    zp += (ev.x + ev.y) + (ev.z + ev.w);
    int b0 = (int)(__float_as_uint(ev.x) >> 20) - 768;
    if (b0 >= 0) { atomicAdd(&hsum[b0], ev.x); atomicAdd(&hcntf[b0], 1.0f); }
    int b1 = (int)(__float_as_uint(ev.y) >> 20) - 768;
    if (b1 >= 0) { atomicAdd(&hsum[b1], ev.y); atomicAdd(&hcntf[b1], 1.0f); }
    int b2 = (int)(__float_as_uint(ev.z) >> 20) - 768;
    if (b2 >= 0) { atomicAdd(&hsum[b2], ev.z); atomicAdd(&hcntf[b2], 1.0f); }
    int b3 = (int)(__float_as_uint(ev.w) >> 20) - 768;
    if (b3 >= 0) { atomicAdd(&hsum[b3], ev.w); atomicAdd(&hcntf[b3], 1.0f); }
  }
  float Z = blockSumF(zp, scr);   // barriers also fence hist atomics + ps writes
  float thr = 0.9f * Z;
  // 3. level scans: crossing bucket = largest value-bucket where
  // (mass above) + (bucket mass) >= thr. Refine to 1 item or exact f32 value.
  for (int lev = 0; lev < 4; lev++) {
    float x  = hsum[255 - tid];
    float xc = hcntf[255 - tid];
    float inclm = blockScanIncl(x, wscr);
    float inclc = blockScanIncl(xc, wscr);
    if (sh_M + inclm >= thr) atomicMin(&sh_cross, tid);
    __syncthreads();
    int ct = sh_cross; if (ct == 256) ct = 255;   // guard (cannot miss)
    if (tid == ct) {
      int key = 255 - tid;
      sh_M = sh_M + (inclm - x);
      sh_C = sh_C + (int)(inclc - xc + 0.5f);
      sh_hs = x; sh_hc = (int)(xc + 0.5f);
      unsigned nlo, nhi;
      if (lev == 0) { nlo = (unsigned)(768 + key) << 20; nhi = nlo + (1u << 20); }
      else {
        int s = (lev == 1) ? 12 : (lev == 2) ? 4 : 0;
        nlo = sh_lo + ((unsigned)key << s); nhi = nlo + (1u << s);
      }
      sh_lo = nlo; sh_hi = nhi;
    }
    __syncthreads();
    if (sh_hc == 1 || lev == 3) break;   // uniform
    hsum[tid] = 0.0f; hcntf[tid] = 0.0f;
    if (tid == 0) sh_cross = 256;
    __syncthreads();
    unsigned rlo = sh_lo, rhi = sh_hi;
    int s2 = (lev == 0) ? 12 : (lev == 1) ? 4 : 0;
    unsigned msk = (lev == 2) ? 15u : 255u;
    for (int j = tid; j < NN; j += 256) {
      unsigned u = __float_as_uint(ps[j]);
      if (u >= rlo && u < rhi) {
        unsigned key = (u >> s2) & msk;
        atomicAdd(&hsum[key], ps[j]); atomicAdd(&hcntf[key], 1.0f);
      }
    }
    __syncthreads();
  }
  // 4. finalize: stop value + tie count (keep while exclusive-prefix < thr)
  if (tid == 0) {
    if (sh_hc == 1) {
      sh_tie = sh_lo; sh_nkt = 1; sh_asum = sh_M + sh_hs; sh_icut = NN;
    } else {
      float tiev = __uint_as_float(sh_lo);
      float cs = sh_M; int n = 0; int nt = sh_hc;
      while (n < nt && cs < thr) { cs += tiev; n++; }
      sh_tie = sh_lo; sh_nkt = n; sh_asum = cs;
      sh_icut = (n == nt) ? NN : ((n == 0) ? -1 : -2);   // -2 => bisect idx
    }
    sh_ntot = sh_C + sh_nkt;
    sh_cnt = 0;
  }
  __syncthreads();
  // 4b. degenerate ties: idx-ascending cutoff
  if (sh_icut == -2) {
    int need = sh_nkt; unsigned tb = sh_tie;
    int lo_ = 0, hi_ = NN - 1;
    for (int it = 0; it < 13; it++) {
      int mid = (lo_ + hi_) >> 1;
      float c = 0.0f;
      for (int j = tid; j < NN; j += 256)
        if (__float_as_uint(ps[j]) == tb && j <= mid) c += 1.0f;
      c = blockSumF(c, scr);
      if (c >= (float)need) hi_ = mid; else lo_ = mid + 1;
    }
    if (tid == 0) sh_icut = hi_;
    __syncthreads();
  }
  // 5. gather: weight = e / sum_kept(e)  (Z cancels)
  unsigned tie = sh_tie; int icut = sh_icut;
  float asum = fmaxf(sh_asum, 1e-12f);
  int ntot = sh_ntot;
  int wid = tid >> 6, lane = tid & 63;
  float4 acc; acc.x = acc.y = acc.z = acc.w = 0.0f;
  if (ntot <= CAND) {
    for (int j = tid; j < NN; j += 256) {
      float p = ps[j]; unsigned u = __float_as_uint(p);
      if (u > tie || (u == tie && j <= icut)) {
        int s = atomicAdd(&sh_cnt, 1);
        cv[s] = p; ci[s] = (ushort_t)j;
      }
    }
    __syncthreads();
    int nc = sh_cnt;
    for (int i = wid; i < nc; i += 4) {
      float pw = cv[i] / asum;
      const float4 xv = *(const float4*)(XaOld + (size_t)ci[i] * D + lane * 4);
      acc.x = fmaf(pw, xv.x, acc.x); acc.y = fmaf(pw, xv.y, acc.y);
      acc.z = fmaf(pw, xv.z, acc.z); acc.w = fmaf(pw, xv.w, acc.w);
    }
  } else {
    for (int j = wid; j < NN; j += 4) {
      float p = ps[j]; unsigned u = __float_as_uint(p);
      if (u > tie || (u == tie && j <= icut)) {
        float pw = p / asum;
        const float4 xv = *(const float4*)(XaOld + (size_t)j * D + lane * 4);
        acc.x = fmaf(pw, xv.x, acc.x); acc.y = fmaf(pw, xv.y, acc.y);
        acc.z = fmaf(pw, xv.z, acc.z); acc.w = fmaf(pw, xv.w, acc.w);
      }
    }
    __syncthreads();
  }
  *(float4*)&wsum[wid][lane * 4] = acc;
  __syncthreads();
  int col = tid;
  float o = (wsum[0][col] + wsum[1][col]) + (wsum[2][col] + wsum[3][col]);
  XaNew[(size_t)(rowBase + blockIdx.x) * D + col] = o;
}

// ---- Z += Xf@U1^T + Xa@U2^T  (4 rows per block) ----
__global__ __launch_bounds__(256) void z_accum(const float* __restrict__ Xf, const float* __restrict__ Xa,
    const float* __restrict__ U1n, const float* __restrict__ U2n, float* __restrict__ Z) {
  __shared__ float xf[4][D];
  __shared__ float xa[4][D];
  int r0 = blockIdx.x * 4, tid = threadIdx.x;
  for (int i = tid; i < 4 * D; i += 256) {
    xf[i >> 8][i & 255] = Xf[(size_t)r0 * D + i];
    xa[i >> 8][i & 255] = Xa[(size_t)r0 * D + i];
  }
  __syncthreads();
  const float* u1r = U1n + (size_t)tid * D;
  const float* u2r = U2n + (size_t)tid * D;
  float a0 = 0, a1 = 0, a2 = 0, a3 = 0, b0 = 0, b1 = 0, b2 = 0, b3 = 0;
  for (int d = 0; d < D; d += 4) {
    float4 u1 = *(const float4*)(u1r + d);
    float4 u2 = *(const float4*)(u2r + d);
    float f1[4] = {u1.x, u1.y, u1.z, u1.w};
    float f2[4] = {u2.x, u2.y, u2.z, u2.w};
#pragma unroll
    for (int j = 0; j < 4; j++) {
      int dd = d + j;
      a0 += xf[0][dd] * f1[j]; a1 += xf[1][dd] * f1[j];
      a2 += xf[2][dd] * f1[j]; a3 += xf[3][dd] * f1[j];
      b0 += xa[0][dd] * f2[j]; b1 += xa[1][dd] * f2[j];
      b2 += xa[2][dd] * f2[j]; b3 += xa[3][dd] * f2[j];
    }
  }
  Z[(size_t)(r0 + 0) * D + tid] += a0 + b0;
  Z[(size_t)(r0 + 1) * D + tid] += a1 + b1;
  Z[(size_t)(r0 + 2) * D + tid] += a2 + b2;
  Z[(size_t)(r0 + 3) * D + tid] += a3 + b3;
}

// ---- out = LayerNorm(X + Z) * g + b ----
__global__ __launch_bounds__(256) void ln_kernel(const float* __restrict__ X, const float* __restrict__ Z,
    const float* __restrict__ g, const float* __restrict__ bb, float* __restrict__ out) {
  __shared__ float scr[4];
  int row = blockIdx.x, tid = threadIdx.x;
  float h = X[(size_t)row * D + tid] + Z[(size_t)row * D + tid];
  float mu = blockSumF(h, scr) * (1.0f / 256.0f);
  float dv = h - mu;
  float var = blockSumF(dv * dv, scr) * (1.0f / 256.0f);
  float o = dv / sqrtf(var + 1e-5f) * g[tid] + bb[tid];
  out[(size_t)row * D + tid] = o;
}

extern "C" void kernel_launch(void* const* d_in, const int* in_sizes, int n_in,
                              void* d_out, int out_size, void* d_ws, size_t ws_size,
                              hipStream_t stream) {
  const float* X  = (const float*)d_in[0];
  const float* S  = (const float*)d_in[1];
  const float* W1 = (const float*)d_in[2];
  const float* W2 = (const float*)d_in[3];
  const float* W3 = (const float*)d_in[4];
  const float* U1 = (const float*)d_in[5];
  const float* U2 = (const float*)d_in[6];
  const float* g  = (const float*)d_in[7];
  const float* b  = (const float*)d_in[8];

  char* w = (char*)d_ws;
  size_t off = 0;
  auto alloc = [&](size_t bytes) {
    void* p = w + off; off += (bytes + 255) & ~(size_t)255; return p;
  };
  float* A1  = (float*)alloc((size_t)NN * D * 4);
  float* A2  = (float*)alloc((size_t)NN * D * 4);
  float* F1  = (float*)alloc((size_t)NN * D * 4);
  float* F2  = (float*)alloc((size_t)NN * D * 4);
  float* Z   = (float*)alloc((size_t)NN * D * 4);
  float* den = (float*)alloc((size_t)NN * 4);
  float* qf  = (float*)alloc((size_t)NN * DA * 4);
  float* kf  = (float*)alloc((size_t)NN * DA * 4);
  int chunk = 512;
  while (chunk > 64 && off + (size_t)chunk * NN * 4 + 4096 > ws_size) chunk >>= 1;
  float* L32 = (float*)alloc((size_t)chunk * NN * 4);
  (void)in_sizes; (void)n_in; (void)out_size;

  zero_kernel<<<1024, 256, 0, stream>>>(Z, (size_t)NN * D);
  rowsum_kernel<<<NN, 256, 0, stream>>>(S, den);

  const float* XaC = X;  float* XaN = A1;
  const float* XfC = X;  float* XfN = F1;
  for (int n = 0; n < 2; n++) {
    xf_gemm<<<dim3(NN / BMX, 4), 256, 0, stream>>>(S, XfC, den, XfN);
    qk32_kernel<<<NN, 64, 0, stream>>>(XaC, W1, W2, W3, qf, kf);
    for (int c = 0; c < NN / chunk; c++) {
      logits32<<<dim3(NN / 64, chunk / 64), 256, 0, stream>>>(qf, kf, L32, c * chunk);
      topp_histsel<<<chunk, 256, 0, stream>>>(L32, XaC, XaN, c * chunk);
    }
    z_accum<<<2048, 256, 0, stream>>>(XfN, XaN, U1 + (size_t)n * D * D, U2 + (size_t)n * D * D, Z);
    XaC = XaN; XaN = A2;
    XfC = XfN; XfN = F2;
  }
  ln_kernel<<<NN, 256, 0, stream>>>(X, Z, g, b, (float*)d_out);
}

// Round 5
// 5213.393 us; speedup vs baseline: 1.2305x; 1.2305x over previous
//
#include <hip/hip_runtime.h>
#include <stdint.h>

#define NN 8192
#define D 256
#define DA 64
#define CAND 2048

typedef unsigned short ushort_t;

// ---- f32 block reductions (256-thread blocks, 4 waves) ----
__device__ float blockSumF(float v, float* scr) {
  __syncthreads();
#pragma unroll
  for (int o = 32; o > 0; o >>= 1) v += __shfl_down(v, o, 64);
  if ((threadIdx.x & 63) == 0) scr[threadIdx.x >> 6] = v;
  __syncthreads();
  return ((scr[0] + scr[1]) + (scr[2] + scr[3]));
}
__device__ float blockMaxF(float v, float* scr) {
  __syncthreads();
#pragma unroll
  for (int o = 32; o > 0; o >>= 1) v = fmaxf(v, __shfl_down(v, o, 64));
  if ((threadIdx.x & 63) == 0) scr[threadIdx.x >> 6] = v;
  __syncthreads();
  return fmaxf(fmaxf(scr[0], scr[1]), fmaxf(scr[2], scr[3]));
}
// ---- inclusive prefix scan across 256 threads (4 waves) ----
__device__ float blockScanIncl(float v, float* wscr) {
#pragma unroll
  for (int off = 1; off < 64; off <<= 1) {
    float u = __shfl_up(v, off, 64);
    if ((threadIdx.x & 63) >= off) v += u;
  }
  __syncthreads();                    // protect wscr reuse
  if ((threadIdx.x & 63) == 63) wscr[threadIdx.x >> 6] = v;
  __syncthreads();
  float add = 0.0f;
  int wid = threadIdx.x >> 6;
  for (int w = 0; w < wid; w++) add += wscr[w];
  return v + add;
}

// ---- zero a float buffer ----
__global__ void zero_kernel(float* __restrict__ p, size_t n) {
  for (size_t i = (size_t)blockIdx.x * blockDim.x + threadIdx.x; i < n;
       i += (size_t)gridDim.x * blockDim.x)
    p[i] = 0.0f;
}

// ---- den[i] = 1 + sum_j S[i][j] ----
__global__ __launch_bounds__(256) void rowsum_kernel(const float* __restrict__ S, float* __restrict__ den) {
  __shared__ float scr[4];
  int row = blockIdx.x, tid = threadIdx.x;
  const float* sr = S + (size_t)row * NN;
  float s = 0;
  for (int c = tid * 4; c < NN; c += 1024) {
    float4 u = *(const float4*)(sr + c);
    s += (u.x + u.y) + (u.z + u.w);
  }
  float tot = blockSumF(s, scr);
  if (tid == 0) den[row] = tot + 1.0f;
}

// ---- split-K partial of S@Xf: 64x64 tile, 4x4/thread, gridZ = K-half ----
// Round-2 proven inner loop (transposed A in LDS, b128 reads). Each K-half
// block atomicAdd's its 4x4 acc into pre-zeroed XfN. Two-operand f32 add is
// commutative => result deterministic regardless of atomic order.
__global__ __launch_bounds__(256) void xf_gemm_sk(const float* __restrict__ S,
                                                  const float* __restrict__ XfC,
                                                  float* __restrict__ XfN) {
  __shared__ float Ast[64][68];   // Ast[k][r] = S[rb+r][kt+k]
  __shared__ float Bs[64][68];    // Bs[k][c]  = XfC[kt+k][cb+c]
  int tid = threadIdx.x;
  int tx = tid & 15, ty = tid >> 4;
  int rb = blockIdx.x * 64;
  int cb = blockIdx.y * 64;
  int k0 = blockIdx.z * (NN / 2);
  float acc[4][4] = {};
  for (int kt = k0; kt < k0 + NN / 2; kt += 64) {
    for (int i = tid; i < 4096; i += 256) {
      int r = i >> 6, c = i & 63;
      Ast[c][r] = S[(size_t)(rb + r) * NN + kt + c];
      Bs[r][c] = XfC[(size_t)(kt + r) * D + cb + c];
    }
    __syncthreads();
#pragma unroll 8
    for (int k = 0; k < 64; k++) {
      float4 av = *(const float4*)&Ast[k][ty * 4];
      float4 bv = *(const float4*)&Bs[k][tx * 4];
      acc[0][0] = fmaf(av.x, bv.x, acc[0][0]); acc[0][1] = fmaf(av.x, bv.y, acc[0][1]);
      acc[0][2] = fmaf(av.x, bv.z, acc[0][2]); acc[0][3] = fmaf(av.x, bv.w, acc[0][3]);
      acc[1][0] = fmaf(av.y, bv.x, acc[1][0]); acc[1][1] = fmaf(av.y, bv.y, acc[1][1]);
      acc[1][2] = fmaf(av.y, bv.z, acc[1][2]); acc[1][3] = fmaf(av.y, bv.w, acc[1][3]);
      acc[2][0] = fmaf(av.z, bv.x, acc[2][0]); acc[2][1] = fmaf(av.z, bv.y, acc[2][1]);
      acc[2][2] = fmaf(av.z, bv.z, acc[2][2]); acc[2][3] = fmaf(av.z, bv.w, acc[2][3]);
      acc[3][0] = fmaf(av.w, bv.x, acc[3][0]); acc[3][1] = fmaf(av.w, bv.y, acc[3][1]);
      acc[3][2] = fmaf(av.w, bv.z, acc[3][2]); acc[3][3] = fmaf(av.w, bv.w, acc[3][3]);
    }
    __syncthreads();
  }
#pragma unroll
  for (int i = 0; i < 4; i++) {
    int r = rb + ty * 4 + i;
#pragma unroll
    for (int j = 0; j < 4; j++) {
      int c = cb + tx * 4 + j;
      atomicAdd(&XfN[(size_t)r * D + c], acc[i][j]);
    }
  }
}

// ---- XfN = (XfN + XfC) / den  (in place, float4) ----
__global__ __launch_bounds__(256) void xf_combine(float* __restrict__ XfN,
                                                  const float* __restrict__ XfC,
                                                  const float* __restrict__ den) {
  size_t i4 = ((size_t)blockIdx.x * 256 + threadIdx.x) * 4;
  int r = (int)(i4 >> 8);
  float dinv = 1.0f / den[r];
  float4 a = *(const float4*)(XfN + i4);
  float4 x = *(const float4*)(XfC + i4);
  float4 o;
  o.x = (a.x + x.x) * dinv; o.y = (a.y + x.y) * dinv;
  o.z = (a.z + x.z) * dinv; o.w = (a.w + x.w) * dinv;
  *(float4*)(XfN + i4) = o;
}

// ---- q,k f32: T1 = Xa@W1^T (materialized), q = T1@W2^T, k = Xa@W3^T ----
__global__ __launch_bounds__(64) void qk32_kernel(const float* __restrict__ Xa,
    const float* __restrict__ W1, const float* __restrict__ W2, const float* __restrict__ W3,
    float* __restrict__ qf, float* __restrict__ kf) {
  __shared__ float x[D];
  __shared__ float ts[DA];
  int row = blockIdx.x, tid = threadIdx.x;
  for (int i = tid; i < D; i += 64) x[i] = Xa[(size_t)row * D + i];
  __syncthreads();
  const float* w1r = W1 + (size_t)tid * D;
  const float* w3r = W3 + (size_t)tid * D;
  float t = 0.0f, kv = 0.0f;
  for (int d = 0; d < D; d++) {
    float xv = x[d];
    t  = fmaf(xv, w1r[d], t);
    kv = fmaf(xv, w3r[d], kv);
  }
  kf[(size_t)row * DA + tid] = kv;
  ts[tid] = t;
  __syncthreads();
  const float* w2r = W2 + (size_t)tid * DA;
  float qv = 0.0f;
  for (int a = 0; a < DA; a++) qv = fmaf(ts[a], w2r[a], qv);
  qf[(size_t)row * DA + tid] = qv;
}

// ---- L[chunk] = q @ k^T  f32 ----
__global__ __launch_bounds__(256) void logits32(const float* __restrict__ qf,
    const float* __restrict__ kf, float* __restrict__ L, int rowBase) {
  __shared__ float qs[64][65];
  __shared__ float ks[64][65];
  int tid = threadIdx.x;
  int tx = tid & 15, ty = tid >> 4;
  int colTile = blockIdx.x * 64;
  int rowTile = blockIdx.y * 64;
  for (int i = tid; i < 4096; i += 256) {
    int r = i >> 6, c = i & 63;
    qs[c][r] = qf[(size_t)(rowBase + rowTile + r) * DA + c];
    ks[c][r] = kf[(size_t)(colTile + r) * DA + c];
  }
  __syncthreads();
  float acc[4][4] = {};
  for (int c = 0; c < 64; c++) {
    float a0 = qs[c][ty * 4], a1 = qs[c][ty * 4 + 1];
    float a2 = qs[c][ty * 4 + 2], a3 = qs[c][ty * 4 + 3];
    float b0 = ks[c][tx * 4], b1 = ks[c][tx * 4 + 1];
    float b2 = ks[c][tx * 4 + 2], b3 = ks[c][tx * 4 + 3];
    acc[0][0] = fmaf(a0, b0, acc[0][0]); acc[0][1] = fmaf(a0, b1, acc[0][1]);
    acc[0][2] = fmaf(a0, b2, acc[0][2]); acc[0][3] = fmaf(a0, b3, acc[0][3]);
    acc[1][0] = fmaf(a1, b0, acc[1][0]); acc[1][1] = fmaf(a1, b1, acc[1][1]);
    acc[1][2] = fmaf(a1, b2, acc[1][2]); acc[1][3] = fmaf(a1, b3, acc[1][3]);
    acc[2][0] = fmaf(a2, b0, acc[2][0]); acc[2][1] = fmaf(a2, b1, acc[2][1]);
    acc[2][2] = fmaf(a2, b2, acc[2][2]); acc[2][3] = fmaf(a2, b3, acc[2][3]);
    acc[3][0] = fmaf(a3, b0, acc[3][0]); acc[3][1] = fmaf(a3, b1, acc[3][1]);
    acc[3][2] = fmaf(a3, b2, acc[3][2]); acc[3][3] = fmaf(a3, b3, acc[3][3]);
  }
#pragma unroll
  for (int i = 0; i < 4; i++)
#pragma unroll
    for (int j = 0; j < 4; j++)
      L[(size_t)(rowTile + ty * 4 + i) * NN + colTile + tx * 4 + j] = acc[i][j];
}

// ---- FULL-ROW top-p via histogram refinement in e-space. ----
// kept-weights = e_j / sum_kept(e); Z only scales the cutoff (cumsum(e) < 0.9*Z).
// One exp pass computes e, Z-partials, histogram. 4-level refinement
// (8/8/8/4 bits) -> exact stop value + idx tie-break. Gather: process ps in
// chunks of CAND (compact kept -> pre-scale -> 8-deep pipelined per-wave
// gather). Handles any nucleus size with latency-hiding loads.
__global__ __launch_bounds__(256) void topp_histsel(const float* __restrict__ L,
    const float* __restrict__ XaOld, float* __restrict__ XaNew, int rowBase) {
  __shared__ float ps[NN];          // 32 KB: logits, then e-values (in place)
  __shared__ float hsum[256];       // per-bucket e-mass
  __shared__ float hcntf[256];      // per-bucket count
  __shared__ float cv[CAND];
  __shared__ ushort_t ci[CAND];
  __shared__ float wsum[4][256];
  __shared__ float wscr[4];
  __shared__ float scr[4];
  __shared__ unsigned sh_lo, sh_hi, sh_tie;
  __shared__ float sh_M, sh_asum, sh_hs;
  __shared__ int sh_cross, sh_hc, sh_icut, sh_nkt, sh_cnt;

  int tid = threadIdx.x;
  const float* Lr = L + (size_t)blockIdx.x * NN;
  // 1. load logits, row max
  float lm = -INFINITY;
  for (int c = tid * 4; c < NN; c += 1024) {
    float4 u = *(const float4*)(Lr + c);
    *(float4*)(ps + c) = u;
    lm = fmaxf(fmaxf(lm, fmaxf(u.x, u.y)), fmaxf(u.z, u.w));
  }
  float m = blockMaxF(lm, scr);   // entry barrier publishes ps
  hsum[tid] = 0.0f; hcntf[tid] = 0.0f;
  if (tid == 0) { sh_M = 0.0f; sh_cross = 256; }
  __syncthreads();
  // 2. single pass: e = exp(l-m) in (0,1] in place; Z partial; histogram.
  // Bucket = (bits>>20)-768. b<0 => e < 2^-31 skipped (rel tail < 4e-6).
  float zp = 0.0f;
  for (int c = tid * 4; c < NN; c += 1024) {
    float4 u = *(const float4*)(ps + c);
    float4 ev;
    ev.x = expf(u.x - m); ev.y = expf(u.y - m);
    ev.z = expf(u.z - m); ev.w = expf(u.w - m);
    *(float4*)(ps + c) = ev;
    zp += (ev.x + ev.y) + (ev.z + ev.w);
    int b0 = (int)(__float_as_uint(ev.x) >> 20) - 768;
    if (b0 >= 0) { atomicAdd(&hsum[b0], ev.x); atomicAdd(&hcntf[b0], 1.0f); }
    int b1 = (int)(__float_as_uint(ev.y) >> 20) - 768;
    if (b1 >= 0) { atomicAdd(&hsum[b1], ev.y); atomicAdd(&hcntf[b1], 1.0f); }
    int b2 = (int)(__float_as_uint(ev.z) >> 20) - 768;
    if (b2 >= 0) { atomicAdd(&hsum[b2], ev.z); atomicAdd(&hcntf[b2], 1.0f); }
    int b3 = (int)(__float_as_uint(ev.w) >> 20) - 768;
    if (b3 >= 0) { atomicAdd(&hsum[b3], ev.w); atomicAdd(&hcntf[b3], 1.0f); }
  }
  float Z = blockSumF(zp, scr);   // barriers also fence hist atomics + ps writes
  float thr = 0.9f * Z;
  // 3. level scans: crossing bucket; refine to 1 item or exact f32 value.
  for (int lev = 0; lev < 4; lev++) {
    float x  = hsum[255 - tid];
    float xc = hcntf[255 - tid];
    float inclm = blockScanIncl(x, wscr);
    float inclc = blockScanIncl(xc, wscr);
    (void)inclc;
    if (sh_M + inclm >= thr) atomicMin(&sh_cross, tid);
    __syncthreads();
    int ct = sh_cross; if (ct == 256) ct = 255;   // guard (cannot miss)
    if (tid == ct) {
      int key = 255 - tid;
      sh_M = sh_M + (inclm - x);
      sh_hs = x; sh_hc = (int)(xc + 0.5f);
      unsigned nlo, nhi;
      if (lev == 0) { nlo = (unsigned)(768 + key) << 20; nhi = nlo + (1u << 20); }
      else {
        int s = (lev == 1) ? 12 : (lev == 2) ? 4 : 0;
        nlo = sh_lo + ((unsigned)key << s); nhi = nlo + (1u << s);
      }
      sh_lo = nlo; sh_hi = nhi;
    }
    __syncthreads();
    if (sh_hc == 1 || lev == 3) break;   // uniform
    hsum[tid] = 0.0f; hcntf[tid] = 0.0f;
    if (tid == 0) sh_cross = 256;
    __syncthreads();
    unsigned rlo = sh_lo, rhi = sh_hi;
    int s2 = (lev == 0) ? 12 : (lev == 1) ? 4 : 0;
    unsigned msk = (lev == 2) ? 15u : 255u;
    for (int j = tid; j < NN; j += 256) {
      unsigned u = __float_as_uint(ps[j]);
      if (u >= rlo && u < rhi) {
        unsigned key = (u >> s2) & msk;
        atomicAdd(&hsum[key], ps[j]); atomicAdd(&hcntf[key], 1.0f);
      }
    }
    __syncthreads();
  }
  // 4. finalize: stop value + tie count (keep while exclusive-prefix < thr)
  if (tid == 0) {
    if (sh_hc == 1) {
      sh_tie = sh_lo; sh_nkt = 1; sh_asum = sh_M + sh_hs; sh_icut = NN;
    } else {
      float tiev = __uint_as_float(sh_lo);
      float cs = sh_M; int n = 0; int nt = sh_hc;
      while (n < nt && cs < thr) { cs += tiev; n++; }
      sh_tie = sh_lo; sh_nkt = n; sh_asum = cs;
      sh_icut = (n == nt) ? NN : ((n == 0) ? -1 : -2);   // -2 => bisect idx
    }
  }
  __syncthreads();
  // 4b. degenerate ties: idx-ascending cutoff
  if (sh_icut == -2) {
    int need = sh_nkt; unsigned tb = sh_tie;
    int lo_ = 0, hi_ = NN - 1;
    for (int it = 0; it < 13; it++) {
      int mid = (lo_ + hi_) >> 1;
      float c = 0.0f;
      for (int j = tid; j < NN; j += 256)
        if (__float_as_uint(ps[j]) == tb && j <= mid) c += 1.0f;
      c = blockSumF(c, scr);
      if (c >= (float)need) hi_ = mid; else lo_ = mid + 1;
    }
    if (tid == 0) sh_icut = hi_;
    __syncthreads();
  }
  // 5. gather in CAND-chunks: compact -> pre-scale -> pipelined per-wave gather
  unsigned tie = sh_tie; int icut = sh_icut;
  float asum = fmaxf(sh_asum, 1e-12f);
  int wid = tid >> 6, lane = tid & 63;
  float4 acc; acc.x = acc.y = acc.z = acc.w = 0.0f;
  for (int base = 0; base < NN; base += CAND) {
    if (tid == 0) sh_cnt = 0;
    __syncthreads();
    for (int j = base + tid; j < base + CAND; j += 256) {
      float p = ps[j]; unsigned u = __float_as_uint(p);
      if (u > tie || (u == tie && j <= icut)) {
        int s = atomicAdd(&sh_cnt, 1);
        cv[s] = p; ci[s] = (ushort_t)j;
      }
    }
    __syncthreads();
    int nc = sh_cnt;
    for (int s = tid; s < nc; s += 256) cv[s] = cv[s] / asum;  // once, not per lane
    __syncthreads();
    int i0 = (nc * wid) >> 2;
    int i1 = (nc * (wid + 1)) >> 2;
    int i = i0;
    for (; i + 8 <= i1; i += 8) {
      float pw[8]; float4 xr[8];
#pragma unroll
      for (int u = 0; u < 8; u++) {
        pw[u] = cv[i + u];
        xr[u] = *(const float4*)(XaOld + (size_t)ci[i + u] * D + lane * 4);
      }
#pragma unroll
      for (int u = 0; u < 8; u++) {
        acc.x = fmaf(pw[u], xr[u].x, acc.x); acc.y = fmaf(pw[u], xr[u].y, acc.y);
        acc.z = fmaf(pw[u], xr[u].z, acc.z); acc.w = fmaf(pw[u], xr[u].w, acc.w);
      }
    }
    for (; i < i1; i++) {
      float pw = cv[i];
      const float4 xv = *(const float4*)(XaOld + (size_t)ci[i] * D + lane * 4);
      acc.x = fmaf(pw, xv.x, acc.x); acc.y = fmaf(pw, xv.y, acc.y);
      acc.z = fmaf(pw, xv.z, acc.z); acc.w = fmaf(pw, xv.w, acc.w);
    }
    __syncthreads();   // cv/ci reused next chunk
  }
  *(float4*)&wsum[wid][lane * 4] = acc;
  __syncthreads();
  int col = tid;
  float o = (wsum[0][col] + wsum[1][col]) + (wsum[2][col] + wsum[3][col]);
  XaNew[(size_t)(rowBase + blockIdx.x) * D + col] = o;
}

// ---- Z += Xf@U1^T + Xa@U2^T  (4 rows per block) ----
__global__ __launch_bounds__(256) void z_accum(const float* __restrict__ Xf, const float* __restrict__ Xa,
    const float* __restrict__ U1n, const float* __restrict__ U2n, float* __restrict__ Z) {
  __shared__ float xf[4][D];
  __shared__ float xa[4][D];
  int r0 = blockIdx.x * 4, tid = threadIdx.x;
  for (int i = tid; i < 4 * D; i += 256) {
    xf[i >> 8][i & 255] = Xf[(size_t)r0 * D + i];
    xa[i >> 8][i & 255] = Xa[(size_t)r0 * D + i];
  }
  __syncthreads();
  const float* u1r = U1n + (size_t)tid * D;
  const float* u2r = U2n + (size_t)tid * D;
  float a0 = 0, a1 = 0, a2 = 0, a3 = 0, b0 = 0, b1 = 0, b2 = 0, b3 = 0;
  for (int d = 0; d < D; d += 4) {
    float4 u1 = *(const float4*)(u1r + d);
    float4 u2 = *(const float4*)(u2r + d);
    float f1[4] = {u1.x, u1.y, u1.z, u1.w};
    float f2[4] = {u2.x, u2.y, u2.z, u2.w};
#pragma unroll
    for (int j = 0; j < 4; j++) {
      int dd = d + j;
      a0 += xf[0][dd] * f1[j]; a1 += xf[1][dd] * f1[j];
      a2 += xf[2][dd] * f1[j]; a3 += xf[3][dd] * f1[j];
      b0 += xa[0][dd] * f2[j]; b1 += xa[1][dd] * f2[j];
      b2 += xa[2][dd] * f2[j]; b3 += xa[3][dd] * f2[j];
    }
  }
  Z[(size_t)(r0 + 0) * D + tid] += a0 + b0;
  Z[(size_t)(r0 + 1) * D + tid] += a1 + b1;
  Z[(size_t)(r0 + 2) * D + tid] += a2 + b2;
  Z[(size_t)(r0 + 3) * D + tid] += a3 + b3;
}

// ---- out = LayerNorm(X + Z) * g + b ----
__global__ __launch_bounds__(256) void ln_kernel(const float* __restrict__ X, const float* __restrict__ Z,
    const float* __restrict__ g, const float* __restrict__ bb, float* __restrict__ out) {
  __shared__ float scr[4];
  int row = blockIdx.x, tid = threadIdx.x;
  float h = X[(size_t)row * D + tid] + Z[(size_t)row * D + tid];
  float mu = blockSumF(h, scr) * (1.0f / 256.0f);
  float dv = h - mu;
  float var = blockSumF(dv * dv, scr) * (1.0f / 256.0f);
  float o = dv / sqrtf(var + 1e-5f) * g[tid] + bb[tid];
  out[(size_t)row * D + tid] = o;
}

extern "C" void kernel_launch(void* const* d_in, const int* in_sizes, int n_in,
                              void* d_out, int out_size, void* d_ws, size_t ws_size,
                              hipStream_t stream) {
  const float* X  = (const float*)d_in[0];
  const float* S  = (const float*)d_in[1];
  const float* W1 = (const float*)d_in[2];
  const float* W2 = (const float*)d_in[3];
  const float* W3 = (const float*)d_in[4];
  const float* U1 = (const float*)d_in[5];
  const float* U2 = (const float*)d_in[6];
  const float* g  = (const float*)d_in[7];
  const float* b  = (const float*)d_in[8];

  char* w = (char*)d_ws;
  size_t off = 0;
  auto alloc = [&](size_t bytes) {
    void* p = w + off; off += (bytes + 255) & ~(size_t)255; return p;
  };
  float* A1  = (float*)alloc((size_t)NN * D * 4);
  float* A2  = (float*)alloc((size_t)NN * D * 4);
  float* F1  = (float*)alloc((size_t)NN * D * 4);
  float* F2  = (float*)alloc((size_t)NN * D * 4);
  float* Z   = (float*)alloc((size_t)NN * D * 4);
  float* den = (float*)alloc((size_t)NN * 4);
  float* qf  = (float*)alloc((size_t)NN * DA * 4);
  float* kf  = (float*)alloc((size_t)NN * DA * 4);
  int chunk = 512;
  while (chunk > 64 && off + (size_t)chunk * NN * 4 + 4096 > ws_size) chunk >>= 1;
  float* L32 = (float*)alloc((size_t)chunk * NN * 4);
  (void)in_sizes; (void)n_in; (void)out_size;

  zero_kernel<<<1024, 256, 0, stream>>>(Z, (size_t)NN * D);
  rowsum_kernel<<<NN, 256, 0, stream>>>(S, den);

  const float* XaC = X;  float* XaN = A1;
  const float* XfC = X;  float* XfN = F1;
  for (int n = 0; n < 2; n++) {
    zero_kernel<<<1024, 256, 0, stream>>>(XfN, (size_t)NN * D);
    xf_gemm_sk<<<dim3(NN / 64, D / 64, 2), 256, 0, stream>>>(S, XfC, XfN);
    xf_combine<<<NN * D / 1024, 256, 0, stream>>>(XfN, XfC, den);
    qk32_kernel<<<NN, 64, 0, stream>>>(XaC, W1, W2, W3, qf, kf);
    for (int c = 0; c < NN / chunk; c++) {
      logits32<<<dim3(NN / 64, chunk / 64), 256, 0, stream>>>(qf, kf, L32, c * chunk);
      topp_histsel<<<chunk, 256, 0, stream>>>(L32, XaC, XaN, c * chunk);
    }
    z_accum<<<2048, 256, 0, stream>>>(XfN, XaN, U1 + (size_t)n * D * D, U2 + (size_t)n * D * D, Z);
    XaC = XaN; XaN = A2;
    XfC = XfN; XfN = F2;
  }
  ln_kernel<<<NN, 256, 0, stream>>>(X, Z, g, b, (float*)d_out);
}